// Round 10
// baseline (187.390 us; speedup 1.0000x reference)
//
#include <hip/hip_runtime.h>

#define NG 50000
#define NCT 64
#define NREF 16
#define NS 1024
#define N0 (NCT * NG)              // 3,200,000  (y0/y1/y2 length)

// d_out layout: out [NS*NG] | y0 [N0] | y1 [N0] | y2 [N0]
#define OFF_Y0 ((size_t)NS * NG)   // 51,200,000
#define OFF_Y1 (OFF_Y0 + N0)
#define OFF_Y2 (OFF_Y1 + N0)

typedef __attribute__((ext_vector_type(8))) short bf16x8;
typedef __attribute__((ext_vector_type(4))) float f32x4;
typedef __attribute__((ext_vector_type(4))) unsigned short u16x4;

__device__ __forceinline__ unsigned short f2bf(float f) {
    union { float f; unsigned u; } v; v.f = f;
    unsigned r = v.u + 0x7fff + ((v.u >> 16) & 1);   // RNE
    return (unsigned short)(r >> 16);
}
__device__ __forceinline__ float bf2f(unsigned short b) {
    union { float f; unsigned u; } v; v.u = ((unsigned)b) << 16;
    return v.f;
}

// ---------------- Kernel 1: RefComb * tile + slice-sum -> y0 ----------------
// y0[j] = sum_{r<16} x[j*16+r] * w_ref[(j%64)*16 + r]
__global__ __launch_bounds__(256) void k_y0(const float* __restrict__ x,
                                            const float* __restrict__ w_ref,
                                            float* __restrict__ y0) {
    __shared__ f32x4 wl[256];                  // 1024 floats of w_ref
    const int tid = threadIdx.x;
    wl[tid] = reinterpret_cast<const f32x4*>(w_ref)[tid];
    __syncthreads();
    const int row = tid & 63;                  // j%64 == tid%64 (stride % 64 == 0)
    const f32x4 w0 = wl[row * 4 + 0];
    const f32x4 w1 = wl[row * 4 + 1];
    const f32x4 w2 = wl[row * 4 + 2];
    const f32x4 w3 = wl[row * 4 + 3];
    const f32x4* x4 = reinterpret_cast<const f32x4*>(x);
    const size_t stride = (size_t)gridDim.x * 256;
    for (size_t j = (size_t)blockIdx.x * 256 + tid; j < (size_t)N0; j += stride) {
        const f32x4* xp = x4 + j * 4;
        f32x4 a = __builtin_nontemporal_load(xp + 0);
        f32x4 b = __builtin_nontemporal_load(xp + 1);
        f32x4 c = __builtin_nontemporal_load(xp + 2);
        f32x4 d = __builtin_nontemporal_load(xp + 3);
        float s = a.x * w0.x + a.y * w0.y + a.z * w0.z + a.w * w0.w
                + b.x * w1.x + b.y * w1.y + b.z * w1.z + b.w * w1.w
                + c.x * w2.x + c.y * w2.y + c.z * w2.z + c.w * w2.w
                + d.x * w3.x + d.y * w3.y + d.z * w3.z + d.w * w3.w;
        y0[j] = s;                             // cached store: gather re-reads y0
    }
}

// ------- Kernel 1b: pre-convert cw (1024x64 fp32) to bf16 hi/lo planes in ws -------
__global__ __launch_bounds__(256) void k_cw(const float* __restrict__ cw,
                                            unsigned short* __restrict__ cwhi,
                                            unsigned short* __restrict__ cwlo) {
    int i = (blockIdx.x * 256 + threadIdx.x) * 4;    // 64 blocks cover 65536
    f32x4 v = *reinterpret_cast<const f32x4*>(cw + i);
    u16x4 h, l;
#pragma unroll
    for (int e = 0; e < 4; ++e) {
        unsigned short hh = f2bf(v[e]);
        h[e] = hh;
        l[e] = f2bf(v[e] - bf2f(hh));
    }
    *reinterpret_cast<u16x4*>(cwhi + i) = h;
    *reinterpret_cast<u16x4*>(cwlo + i) = l;
}

// ------- Kernel 2 (fused): gather + scale + stretch + MFMA conv -------
// Per 64-gene block:
//   Phase A: 16-deep pipelined random gather (idx c-major coalesced) -> T[c][g] LDS
//   Phase B: y1/y2 NT-stores (g-major coalesced) + build hi/lo bf16 A-tile [g][c]
//   Chunk loop (8x, NO barriers): B-frags direct from L2-resident cw (bf16 planes if
//   PRECONV, else fp32+in-reg convert), 48 MFMA, NT-store out.
// MFMA: A = y2-tile (M=g,K=c), B = cw^T (K=c,N=s); split fp32 = hi+lo bf16,
// acc += Ah*Bh + Ah*Bl + Al*Bh. D layout (m89): col=lane&15 -> s, row=(lane>>4)*4+reg -> g.
#define STILE 128
template<bool PRECONV>
__global__ __launch_bounds__(256) void k_fused(const float* __restrict__ y0,
                                               const int* __restrict__ idx,
                                               const float* __restrict__ w_ct,
                                               const float* __restrict__ w_stretch,
                                               const float* __restrict__ cw,
                                               const unsigned short* __restrict__ cwhi,
                                               const unsigned short* __restrict__ cwlo,
                                               float* __restrict__ y1,
                                               float* __restrict__ y2,
                                               float* __restrict__ out) {
    __shared__ float T[64 * 65];                     // [c][g] gather tile (16640 B)
    __shared__ unsigned short Yhi[64 * 72];          // [g][c] A-tile hi (9216 B)
    __shared__ unsigned short Ylo[64 * 72];          // [g][c] A-tile lo (9216 B)

    const int tid = threadIdx.x;
    const int g0 = blockIdx.x * 64;

    // ---- Phase A: gather, 16-deep MLP (ids then vals) ----
    int ids[16];
#pragma unroll
    for (int k = 0; k < 16; ++k) {
        int lin = k * 256 + tid;
        int c = lin >> 6, gl = lin & 63;
        int gc = min(g0 + gl, NG - 1);               // clamp; garbage rows masked at stores
        ids[k] = idx[c * NG + gc];
    }
    float vals[16];
#pragma unroll
    for (int k = 0; k < 16; ++k) vals[k] = y0[ids[k]];
#pragma unroll
    for (int k = 0; k < 16; ++k) {
        int lin = k * 256 + tid;
        int c = lin >> 6, gl = lin & 63;
        T[c * 65 + gl] = vals[k];
    }
    __syncthreads();

    // ---- Phase B: y1/y2 out + hi/lo A-tile ----
#pragma unroll
    for (int k = 0; k < 16; ++k) {
        int lin = k * 256 + tid;
        int gl = lin >> 6, c = lin & 63;             // gl wave-uniform per k
        int g = g0 + gl;
        float t = T[c * 65 + gl];                    // (c+gl)%32 banks: 2-way, free
        float v1 = t * w_ct[c];
        float v2 = v1 * w_stretch[min(g, NG - 1)];   // wave-uniform scalar load
        int base = gl * 72 + c;
        unsigned short h = f2bf(v2);
        Yhi[base] = h;
        Ylo[base] = f2bf(v2 - bf2f(h));
        if (g < NG) {
            size_t o = (size_t)g * 64 + c;
            __builtin_nontemporal_store(v1, y1 + o);
            __builtin_nontemporal_store(v2, y2 + o);
        }
    }
    __syncthreads();

    const int lane = tid & 63;
    const int wid  = tid >> 6;                       // 0..3
    const int l15  = lane & 15;
    const int l4   = lane >> 4;                      // 0..3
    const int nb   = wid * 32;                       // wave's local s base

    // A fragments: loaded once per block, live in regs for the whole chunk loop
    bf16x8 Ah[4][2], Al[4][2];
#pragma unroll
    for (int m = 0; m < 4; ++m) {
        int grow = m * 16 + l15;
#pragma unroll
        for (int ks = 0; ks < 2; ++ks) {
            int koff = ks * 32 + l4 * 8;
            Ah[m][ks] = *reinterpret_cast<const bf16x8*>(&Yhi[grow * 72 + koff]);
            Al[m][ks] = *reinterpret_cast<const bf16x8*>(&Ylo[grow * 72 + koff]);
        }
    }

    // ---- Chunk loop over samples: barrier-free ----
    for (int s0 = 0; s0 < NS; s0 += STILE) {
        f32x4 acc[4][2];
#pragma unroll
        for (int m = 0; m < 4; ++m)
#pragma unroll
            for (int n = 0; n < 2; ++n) acc[m][n] = (f32x4){0.f, 0.f, 0.f, 0.f};

#pragma unroll
        for (int n = 0; n < 2; ++n) {
            const size_t srow = (size_t)(s0 + nb + n * 16 + l15) * 64;
            bf16x8 Bh[2], Bl[2];
#pragma unroll
            for (int ks = 0; ks < 2; ++ks) {
                int koff = ks * 32 + l4 * 8;
                if (PRECONV) {
                    Bh[ks] = *reinterpret_cast<const bf16x8*>(cwhi + srow + koff);
                    Bl[ks] = *reinterpret_cast<const bf16x8*>(cwlo + srow + koff);
                } else {
                    f32x4 va = *reinterpret_cast<const f32x4*>(cw + srow + koff);
                    f32x4 vb = *reinterpret_cast<const f32x4*>(cw + srow + koff + 4);
#pragma unroll
                    for (int e = 0; e < 4; ++e) {
                        unsigned short h = f2bf(va[e]);
                        Bh[ks][e] = (short)h;
                        Bl[ks][e] = (short)f2bf(va[e] - bf2f(h));
                        h = f2bf(vb[e]);
                        Bh[ks][e + 4] = (short)h;
                        Bl[ks][e + 4] = (short)f2bf(vb[e] - bf2f(h));
                    }
                }
            }
#pragma unroll
            for (int m = 0; m < 4; ++m)
#pragma unroll
                for (int ks = 0; ks < 2; ++ks) {
                    acc[m][n] = __builtin_amdgcn_mfma_f32_16x16x32_bf16(Ah[m][ks], Bh[ks], acc[m][n], 0, 0, 0);
                    acc[m][n] = __builtin_amdgcn_mfma_f32_16x16x32_bf16(Ah[m][ks], Bl[ks], acc[m][n], 0, 0, 0);
                    acc[m][n] = __builtin_amdgcn_mfma_f32_16x16x32_bf16(Al[m][ks], Bh[ks], acc[m][n], 0, 0, 0);
                }
        }

        // NT stores: lane's 4 regs = 4 consecutive genes => f32x4
#pragma unroll
        for (int m = 0; m < 4; ++m) {
            int g4 = g0 + m * 16 + l4 * 4;
            if (g4 < NG) {
#pragma unroll
                for (int n = 0; n < 2; ++n) {
                    int s = s0 + nb + n * 16 + l15;
                    __builtin_nontemporal_store(acc[m][n], reinterpret_cast<f32x4*>(out + (size_t)s * NG + g4));
                }
            }
        }
    }
}

extern "C" void kernel_launch(void* const* d_in, const int* in_sizes, int n_in,
                              void* d_out, int out_size, void* d_ws, size_t ws_size,
                              hipStream_t stream) {
    const float* x         = (const float*)d_in[0];
    const int*   idx       = (const int*)d_in[1];
    const float* w_ref     = (const float*)d_in[2];
    const float* w_ct      = (const float*)d_in[3];
    const float* w_stretch = (const float*)d_in[4];
    const float* conv_w    = (const float*)d_in[5];

    float* out = (float*)d_out;
    float* y0  = out + OFF_Y0;
    float* y1  = out + OFF_Y1;
    float* y2  = out + OFF_Y2;

    k_y0<<<2048, 256, 0, stream>>>(x, w_ref, y0);

    const bool preconv = (ws_size >= (size_t)NS * NCT * 2 * sizeof(unsigned short));
    unsigned short* cwhi = (unsigned short*)d_ws;
    unsigned short* cwlo = cwhi + NS * NCT;
    if (preconv) {
        k_cw<<<NS * NCT / 1024, 256, 0, stream>>>(conv_w, cwhi, cwlo);
        k_fused<true><<<(NG + 63) / 64, 256, 0, stream>>>(y0, idx, w_ct, w_stretch, conv_w,
                                                          cwhi, cwlo, y1, y2, out);
    } else {
        k_fused<false><<<(NG + 63) / 64, 256, 0, stream>>>(y0, idx, w_ct, w_stretch, conv_w,
                                                           cwhi, cwlo, y1, y2, out);
    }
}